// Round 1
// baseline (1735.550 us; speedup 1.0000x reference)
//
#include <hip/hip_runtime.h>

// 5-layer GRU, H=20, B=256, T=4096, fp32. PyTorch GRU math.
// One block per batch element; 5 waves per block = one wave per layer,
// wavefront-pipelined across chunks of K=16 timesteps.
// Lane g (<60) owns gate g (rows of W_ih/W_hh in registers).
// h broadcast for the recurrent matvec via v_readlane (no LDS round trip);
// cross-gate gather (r/z/n) via __shfl (ds_bpermute).

#define HH 20
#define GG 60
#define NL 5
#define BB 256
#define TT 4096
#define KK 16
#define NC (TT / KK)

struct Params {
  const float* x;
  const float* wih[NL];
  const float* whh[NL];
  const float* bih[NL];
  const float* bhh[NL];
  const float* wout;
  const float* bout;
  float* out;
};

__device__ __forceinline__ float lane_bcast(float v, int j) {
  return __int_as_float(__builtin_amdgcn_readlane(__float_as_int(v), j));
}
__device__ __forceinline__ float fast_sig(float x) {
  float e = __expf(-x);
  return __builtin_amdgcn_rcpf(1.0f + e);
}
__device__ __forceinline__ float fast_tanh(float x) {
  x = fminf(fmaxf(x, -15.0f), 15.0f);   // avoid inf/inf -> NaN
  float e = __expf(-2.0f * x);
  return (1.0f - e) * __builtin_amdgcn_rcpf(1.0f + e);
}

__global__ __launch_bounds__(NL * 64) void gru5_kernel(Params p) {
  // double-buffered layer->layer handoff (layers 0..3 produce for 1..4)
  __shared__ __align__(16) float hbuf[2][NL - 1][KK][HH];
  __shared__ float yp[NL];

  const int tid = threadIdx.x;
  const int l = tid >> 6;        // wave index == layer
  const int lane = tid & 63;
  const int b = blockIdx.x;
  const int g = lane < GG ? lane : GG - 1;  // gate owned by this lane (clamped)

  // --- load this wave's weight rows into registers ---
  float whh_r[HH];
  {
    const float* W = p.whh[l];
    #pragma unroll
    for (int j = 0; j < HH; ++j) whh_r[j] = W[g * HH + j];
  }
  const float bi = p.bih[l][g];
  const float bh = p.bhh[l][g];
  float wih_r[HH];
  if (l == 0) {
    wih_r[0] = p.wih[0][g];      // input size 1
  } else {
    const float* W = p.wih[l];
    #pragma unroll
    for (int j = 0; j < HH; ++j) wih_r[j] = W[g * HH + j];
  }

  float hreg = 0.0f;             // lanes 0..19 carry h[i]
  float xg[KK];                  // input projection for the chunk (per-gate)

  const float* xrow = p.x + (size_t)b * TT;
  float* hout = p.out + (size_t)b * TT * HH;

  for (int s = 0; s < NC + NL - 1; ++s) {
    const int c = s - l;         // this wave's chunk index (wave-uniform)
    if (c >= 0 && c < NC) {
      const int pr = (s + 1) & 1;  // read buffer (written at step s-1)
      const int pc = s & 1;        // write buffer

      // ---- phase A: input projections for all K timesteps (full ILP) ----
      if (l == 0) {
        const float4* xp = (const float4*)(xrow + c * KK);
        float4 xv[KK / 4];
        #pragma unroll
        for (int q = 0; q < KK / 4; ++q) xv[q] = xp[q];
        const float* xs = (const float*)xv;
        #pragma unroll
        for (int t = 0; t < KK; ++t) xg[t] = fmaf(wih_r[0], xs[t], bi);
      } else {
        #pragma unroll
        for (int t = 0; t < KK; ++t) {
          float4 hv4[5];
          const float4* hin4 = (const float4*)(&hbuf[pr][l - 1][t][0]);
          #pragma unroll
          for (int q = 0; q < 5; ++q) hv4[q] = hin4[q];
          const float* hv = (const float*)hv4;
          float a0 = bi, a1 = 0.f, a2 = 0.f, a3 = 0.f;
          #pragma unroll
          for (int j = 0; j < HH; j += 4) {
            a0 = fmaf(wih_r[j],     hv[j],     a0);
            a1 = fmaf(wih_r[j + 1], hv[j + 1], a1);
            a2 = fmaf(wih_r[j + 2], hv[j + 2], a2);
            a3 = fmaf(wih_r[j + 3], hv[j + 3], a3);
          }
          xg[t] = (a0 + a1) + (a2 + a3);
        }
      }

      // ---- phase B: the serial recurrence over the chunk ----
      #pragma unroll
      for (int t = 0; t < KK; ++t) {
        float a0 = bh, a1 = 0.f, a2 = 0.f, a3 = 0.f;
        #pragma unroll
        for (int j = 0; j < HH; j += 4) {
          a0 = fmaf(whh_r[j],     lane_bcast(hreg, j),     a0);
          a1 = fmaf(whh_r[j + 1], lane_bcast(hreg, j + 1), a1);
          a2 = fmaf(whh_r[j + 2], lane_bcast(hreg, j + 2), a2);
          a3 = fmaf(whh_r[j + 3], lane_bcast(hreg, j + 3), a3);
        }
        const float gh = (a0 + a1) + (a2 + a3);   // (W_hh h + b_hh)[g]
        const float sv = xg[t] + gh;              // x-proj + h-proj (r,z gates)
        const float az = __shfl(sv, lane + 20);   // z-gate sum for hidden i
        const float xn = __shfl(xg[t], lane + 40);// x-proj of n gate
        const float hn = __shfl(gh, lane + 40);   // h-proj of n gate (incl b_hh)
        const float r = fast_sig(sv);             // lanes <20: r_i
        const float z = fast_sig(az);
        const float n = fast_tanh(fmaf(r, hn, xn));
        hreg = fmaf(z, hreg - n, n);              // (1-z)*n + z*h
        if (lane < HH) {
          if (l < NL - 1) hbuf[pc][l][t][lane] = hreg;
          else hout[(size_t)(c * KK + t) * HH + lane] = hreg;
        }
      }

      // ---- epilogue at last chunk: h_n + y_hat partial ----
      if (c == NC - 1) {
        if (lane < HH)
          p.out[(size_t)BB * TT * HH + (size_t)b * NL * HH + l * HH + lane] = hreg;
        float pp = (lane < HH) ? hreg * p.wout[l * HH + lane] : 0.0f;
        #pragma unroll
        for (int off = 32; off > 0; off >>= 1) pp += __shfl_down(pp, off);
        if (lane == 0) yp[l] = pp;
      }
    }
    __syncthreads();
  }

  if (tid == 0) {
    float y = p.bout[0];
    #pragma unroll
    for (int ll = 0; ll < NL; ++ll) y += yp[ll];
    p.out[(size_t)BB * TT * HH + (size_t)BB * NL * HH + b] = y;
  }
}

extern "C" void kernel_launch(void* const* d_in, const int* in_sizes, int n_in,
                              void* d_out, int out_size, void* d_ws, size_t ws_size,
                              hipStream_t stream) {
  Params p;
  p.x = (const float*)d_in[0];
  for (int l = 0; l < NL; ++l) {
    p.wih[l] = (const float*)d_in[1 + 4 * l];
    p.whh[l] = (const float*)d_in[2 + 4 * l];
    p.bih[l] = (const float*)d_in[3 + 4 * l];
    p.bhh[l] = (const float*)d_in[4 + 4 * l];
  }
  p.wout = (const float*)d_in[1 + 4 * NL];
  p.bout = (const float*)d_in[2 + 4 * NL];
  p.out = (float*)d_out;

  gru5_kernel<<<BB, NL * 64, 0, stream>>>(p);
}